// Round 16
// baseline (293.498 us; speedup 1.0000x reference)
//
#include <hip/hip_runtime.h>
#include <math.h>

typedef unsigned int u32;
typedef unsigned long long u64;
typedef _Float16 f16x8 __attribute__((ext_vector_type(8)));
typedef _Float16 f16x4 __attribute__((ext_vector_type(4)));
typedef float f32x4 __attribute__((ext_vector_type(4)));
typedef __attribute__((address_space(1))) const char gch;
typedef __attribute__((address_space(3))) char lch;

#define ZD 256      // z_dim (C)
#define KC 1024     // number of codes
#define TT 4096     // T
#define BB 16       // B
#define NROWS (BB*TT)     // 65536
#define TAU 0.12f         // margin threshold (~6 sigma of fp16 pairwise err)
#define FLAGCAP 32768

__device__ __forceinline__ u32 flip32(float s) {
    int i = __float_as_int(s);
    return (u32)(i ^ ((i >> 31) | 0x80000000));
}
__device__ __forceinline__ float unflip32(u32 u) {
    int m = (~(((int)u) >> 31)) | 0x80000000;
    return __int_as_float((int)(u ^ (u32)m));
}

// ---------------- prep: zero cnt/done/scal, re=||e||^2, emb->fp16 ----------------
__global__ __launch_bounds__(256)
void vq_prep_kernel(const float* __restrict__ emb, _Float16* __restrict__ eh,
                    float* __restrict__ re, int* __restrict__ cnt,
                    float* __restrict__ scal) {
    int gid = blockIdx.x * 256 + threadIdx.x;
    if (gid < 4)  scal[gid] = 0.f;
    if (gid < 2)  cnt[gid] = 0;      // cnt[0]=flag count, cnt[1]=done ticket

    int code = gid >> 6;   // one wave per code
    int lane = threadIdx.x & 63;
    float4 v = *(const float4*)(emb + (size_t)code * ZD + lane * 4);
    float s = v.x*v.x + v.y*v.y + v.z*v.z + v.w*v.w;
    #pragma unroll
    for (int off = 32; off; off >>= 1) s += __shfl_down(s, off, 64);
    if (lane == 0) re[code] = s;

    f16x4 hv;
    hv[0] = (_Float16)v.x; hv[1] = (_Float16)v.y;
    hv[2] = (_Float16)v.z; hv[3] = (_Float16)v.w;
    *(f16x4*)(eh + (size_t)code * ZD + lane * 4) = hv;
}

// ---- stage one 32-code half-tile (16KB) via global_load_lds; 4 waves x 4 loads ----
__device__ __forceinline__ void stage_half4(const char* ehc, char* dstbase,
                                            int h, int w, int l) {
    const int srow = h * 16384;             // 32 codes * 512B
    #pragma unroll
    for (int j = 0; j < 4; ++j) {
        const int gi  = w * 4 + j;          // 0..15
        const int c   = 2 * gi + (l >> 5);  // local code this lane's 16B lands in
        const int kbs = (l & 31) * 16;
        const int off = srow + c * 512 + (kbs ^ ((c & 7) << 4));
        __builtin_amdgcn_global_load_lds((gch*)(ehc + off),
                                         (lch*)(dstbase + gi * 1024), 16, 0, 0);
    }
}

// ---- one 32-code compute phase: 16 ds_read_b128 + 32 MFMA (2 rowgroups) ----
__device__ __forceinline__ void compute_phase32(const char* hb, int h,
                                                const f16x8 (&ah)[2][8], const float* reL,
                                                float (&v1)[8], float (&v2)[8], int (&i1)[8],
                                                int lane15, int lk) {
    #pragma unroll
    for (int cg = 0; cg < 2; ++cg) {
        const int c  = cg * 16 + lane15;        // local code 0..31
        const int sw = (lane15 & 7) << 4;       // c&7 == lane15&7
        f16x8 bh[8];
        #pragma unroll
        for (int ks = 0; ks < 8; ++ks)
            bh[ks] = *(const f16x8*)(hb + c * 512 + ((lk * 16 + ks * 64) ^ sw));

        f32x4 a0 = {0.f, 0.f, 0.f, 0.f};
        f32x4 a1 = {0.f, 0.f, 0.f, 0.f};
        __builtin_amdgcn_s_setprio(1);
        #pragma unroll
        for (int ks = 0; ks < 8; ++ks) {
            a0 = __builtin_amdgcn_mfma_f32_16x16x32_f16(ah[0][ks], bh[ks], a0, 0, 0, 0);
            a1 = __builtin_amdgcn_mfma_f32_16x16x32_f16(ah[1][ks], bh[ks], a1, 0, 0, 0);
        }
        __builtin_amdgcn_s_setprio(0);

        const int codeg = h * 32 + c;
        const float rc = reL[codeg];
        #pragma unroll
        for (int r = 0; r < 4; ++r) {
            float s0 = fmaf(-2.f, a0[r], rc);
            float n2a = fminf(fmaxf(v1[r], s0), v2[r]);          // med3(v1,v2,s0)
            i1[r] = (s0 < v1[r]) ? codeg : i1[r];
            v1[r] = fminf(v1[r], s0);
            v2[r] = n2a;
            float s1 = fmaf(-2.f, a1[r], rc);
            float n2b = fminf(fmaxf(v1[4 + r], s1), v2[4 + r]);
            i1[4 + r] = (s1 < v1[4 + r]) ? codeg : i1[4 + r];
            v1[4 + r] = fminf(v1[4 + r], s1);
            v2[4 + r] = n2b;
        }
    }
}

// ---------------- fused argmin + out-write + loss + idx + sparsity partial ----------------
// 512 blocks x 256 threads (4 waves). Block: 128 rows; wave w: rows [32w,32w+32).
// z staged coalesced via global_load_lds; 32 phases, ring-4 LDS, counted vmcnt(8).
// Epilogue: sparsity (E E^T logsumexp) partial for rows [2*bid, 2*bid+2) -> spar[bid].
__global__ __launch_bounds__(256, 2)
void vq_argmin_mfma(const float* __restrict__ z, const _Float16* __restrict__ eh,
                    const float* __restrict__ emb, const float* __restrict__ re,
                    float* __restrict__ out, float* __restrict__ scal,
                    int* __restrict__ idx, int* __restrict__ cnt,
                    int* __restrict__ flags, float* __restrict__ spar) {
    __shared__ __align__(16) char lds[71168];   // ring 4x16KB | reL 4KB | tails
    float* reL   = (float*)(lds + 65536);   // 1024 f32
    float* zsqL  = (float*)(lds + 69632);   // 128 f32
    int*   idsL  = (int*)  (lds + 70144);   // 128 i32
    float* lossL = (float*)(lds + 70656);   // 128 f32

    const int tid = threadIdx.x;
    const int w   = tid >> 6;       // 0..3
    const int l   = tid & 63;
    const int lane15 = l & 15;
    const int lk     = l >> 4;
    const int r0  = blockIdx.x * 128;
    const int b   = r0 >> 12;
    const int t0  = r0 & 4095;
    const char* ehc = (const char*)eh;

    *(float4*)(reL + tid * 4) = *(const float4*)(re + tid * 4);

    // ---- z prologue: coalesced glds staging into ring[w] (16KB), 2 rounds of 128 c ----
    f16x8 ah[2][8];
    float zsq[2] = {0.f, 0.f};
    {
        const char* zb = (const char*)(z + (size_t)b * ZD * TT + t0 + w * 32);
        char* zdst = lds + w * 16384;
        #pragma unroll
        for (int round = 0; round < 2; ++round) {
            #pragma unroll
            for (int j = 0; j < 16; ++j) {
                const int c  = round * 128 + j * 8 + (l >> 3);
                const int tb = (l & 7) * 16;
                const char* src = zb + (size_t)c * TT * 4 + tb;
                __builtin_amdgcn_global_load_lds((gch*)src, (lch*)(zdst + j * 1024),
                                                 16, 0, 0);
            }
            asm volatile("s_waitcnt vmcnt(0)" ::: "memory");
            __builtin_amdgcn_sched_barrier(0);
            #pragma unroll
            for (int rg = 0; rg < 2; ++rg) {
                const int tw = rg * 16 + lane15;
                #pragma unroll
                for (int ks2 = 0; ks2 < 4; ++ks2) {
                    const int cl = ks2 * 32 + lk * 8;   // local c within round
                    f16x8 h;
                    #pragma unroll
                    for (int j = 0; j < 8; ++j) {
                        float v = *(const float*)(zdst + (cl + j) * 128 + tw * 4);
                        zsq[rg] = fmaf(v, v, zsq[rg]);
                        h[j] = (_Float16)v;
                    }
                    ah[rg][round * 4 + ks2] = h;
                }
            }
            asm volatile("s_waitcnt lgkmcnt(0)" ::: "memory");  // reads done before reuse
            __builtin_amdgcn_sched_barrier(0);
        }
    }
    #pragma unroll
    for (int rg = 0; rg < 2; ++rg) {
        zsq[rg] += __shfl_xor(zsq[rg], 16, 64);
        zsq[rg] += __shfl_xor(zsq[rg], 32, 64);
        if (l < 16) zsqL[w * 32 + rg * 16 + l] = zsq[rg];
    }

    float v1[8], v2[8];
    int   i1[8];
    #pragma unroll
    for (int s8 = 0; s8 < 8; ++s8) { v1[s8] = 3.4e38f; v2[s8] = 3.4e38f; i1[s8] = 0; }

    // all waves done using ring as z-scratch; drain ds ops, then begin e-staging
    asm volatile("s_waitcnt vmcnt(0) lgkmcnt(0)" ::: "memory");
    __syncthreads();
    stage_half4(ehc, lds,         0, w, l);
    stage_half4(ehc, lds + 16384, 1, w, l);
    stage_half4(ehc, lds + 32768, 2, w, l);

    // Phase h reads buf[h&3]; stage(h+3) (issued after the phase-h barrier) writes
    // buf[(h-1)&3], whose reads finished at that barrier. At the wait, stages h+1
    // and h+2 are outstanding (4 loads each) -> vmcnt(8) guarantees stage h landed.
    for (int h = 0; h < 30; ++h) {
        asm volatile("s_waitcnt vmcnt(8)" ::: "memory");
        __builtin_amdgcn_sched_barrier(0);
        __builtin_amdgcn_s_barrier();
        if (h < 29) stage_half4(ehc, lds + ((h + 3) & 3) * 16384, h + 3, w, l);
        compute_phase32(lds + (h & 3) * 16384, h, ah, reL, v1, v2, i1, lane15, lk);
    }
    asm volatile("s_waitcnt vmcnt(4)" ::: "memory");
    __builtin_amdgcn_sched_barrier(0);
    __builtin_amdgcn_s_barrier();
    compute_phase32(lds + (30 & 3) * 16384, 30, ah, reL, v1, v2, i1, lane15, lk);
    asm volatile("s_waitcnt vmcnt(0)" ::: "memory");
    __builtin_amdgcn_sched_barrier(0);
    __builtin_amdgcn_s_barrier();
    compute_phase32(lds + (31 & 3) * 16384, 31, ah, reL, v1, v2, i1, lane15, lk);

    // reduce across the 16 lanes holding different codes (same rows)
    #pragma unroll
    for (int off = 1; off < 16; off <<= 1) {
        #pragma unroll
        for (int s8 = 0; s8 < 8; ++s8) {
            float ov1 = __shfl_xor(v1[s8], off, 64);
            int   oi1 = __shfl_xor(i1[s8], off, 64);
            float ov2 = __shfl_xor(v2[s8], off, 64);
            float nv2 = fminf(fmaxf(v1[s8], ov1), fminf(v2[s8], ov2));
            if (ov1 < v1[s8] || (ov1 == v1[s8] && oi1 < i1[s8])) { v1[s8] = ov1; i1[s8] = oi1; }
            v2[s8] = nv2;
        }
    }
    if (lane15 == 0) {
        #pragma unroll
        for (int s8 = 0; s8 < 8; ++s8) {
            const int rg = s8 >> 2, rr = s8 & 3;
            const int row = w * 32 + rg * 16 + lk * 4 + rr;   // local row 0..127
            idsL[row] = i1[s8];
            const bool fl = (v2[s8] - v1[s8] < TAU);
            lossL[row] = fl ? zsqL[row] : (zsqL[row] + v1[s8]);
            if (fl) {
                int p = atomicAdd(cnt, 1);
                if (p < FLAGCAP) flags[p] = (r0 + row) | (i1[s8] << 16);
            }
        }
    }
    __syncthreads();

    // idx store (coalesced) + block loss reduce
    if (tid < 128) {
        idx[r0 + tid] = idsL[tid];
        float lv = lossL[tid];
        #pragma unroll
        for (int off = 32; off; off >>= 1) lv += __shfl_down(lv, off, 64);
        if (l == 0) { atomicAdd(scal + 0, lv); atomicAdd(scal + 1, lv); }
    }

    // out-write: wave w covers c in [64w, 64w+64), all 128 rows
    {
        const int c0 = w * 64;
        float* ob = out + (size_t)b * ZD * TT + t0;
        #pragma unroll
        for (int half = 0; half < 2; ++half) {
            const int tt = half * 64 + l;
            const int ii = idsL[tt];
            const float4* er4 = (const float4*)(emb + (size_t)ii * ZD + c0);
            #pragma unroll
            for (int c4 = 0; c4 < 16; ++c4) {
                float4 ev = er4[c4];
                float* o0 = ob + (size_t)(c0 + c4 * 4) * TT + tt;
                o0[0]      = ev.x;
                o0[TT]     = ev.y;
                o0[2 * TT] = ev.z;
                o0[3 * TT] = ev.w;
            }
        }
    }

    // ---- sparsity partial for rows [2*bid, 2*bid+2), reusing free ring LDS ----
    {
        float* erS   = (float*)lds;             // 512 f32 (2 rows)
        float* wmaxS = (float*)(lds + 2048);    // [2][4]
        float* wsumS = (float*)(lds + 2112);    // [2][4]
        float* shDS  = (float*)(lds + 2176);    // [2]
        const int r0s = blockIdx.x * 2;
        __syncthreads();        // all waves past main loop & idx phase; ring free
        erS[tid]       = emb[(size_t)r0s * ZD + tid];
        erS[256 + tid] = emb[(size_t)r0s * ZD + 256 + tid];
        __syncthreads();

        float dots[4][2];
        #pragma unroll
        for (int cc = 0; cc < 4; ++cc) {
            const int c = cc * 256 + tid;
            const float4* ec = (const float4*)(emb + (size_t)c * ZD);
            float a0 = 0.f, a1 = 0.f;
            for (int k4 = 0; k4 < ZD / 4; ++k4) {
                float4 e4 = ec[k4];
                const float* p0 = &erS[k4 * 4];
                const float* p1 = &erS[256 + k4 * 4];
                a0 = fmaf(e4.x, p0[0], fmaf(e4.y, p0[1], fmaf(e4.z, p0[2], fmaf(e4.w, p0[3], a0))));
                a1 = fmaf(e4.x, p1[0], fmaf(e4.y, p1[1], fmaf(e4.z, p1[2], fmaf(e4.w, p1[3], a1))));
            }
            dots[cc][0] = a0; dots[cc][1] = a1;
            const int gr = c - r0s;
            if (gr == 0) shDS[0] = a0;
            if (gr == 1) shDS[1] = a1;
        }
        #pragma unroll
        for (int r = 0; r < 2; ++r) {
            float m = fmaxf(fmaxf(dots[0][r], dots[1][r]), fmaxf(dots[2][r], dots[3][r]));
            #pragma unroll
            for (int off = 32; off; off >>= 1) m = fmaxf(m, __shfl_xor(m, off, 64));
            if (l == 0) wmaxS[r * 4 + w] = m;
        }
        __syncthreads();
        #pragma unroll
        for (int r = 0; r < 2; ++r) {
            const float M = fmaxf(fmaxf(wmaxS[r * 4], wmaxS[r * 4 + 1]),
                                  fmaxf(wmaxS[r * 4 + 2], wmaxS[r * 4 + 3]));
            float se = expf(dots[0][r] - M) + expf(dots[1][r] - M)
                     + expf(dots[2][r] - M) + expf(dots[3][r] - M);
            #pragma unroll
            for (int off = 32; off; off >>= 1) se += __shfl_xor(se, off, 64);
            if (l == 0) wsumS[r * 4 + w] = se;
        }
        __syncthreads();
        if (tid == 0) {
            float acc2 = 0.f;
            #pragma unroll
            for (int r = 0; r < 2; ++r) {
                const float M = fmaxf(fmaxf(wmaxS[r * 4], wmaxS[r * 4 + 1]),
                                      fmaxf(wmaxS[r * 4 + 2], wmaxS[r * 4 + 3]));
                const float S = wsumS[r * 4] + wsumS[r * 4 + 1]
                              + wsumS[r * 4 + 2] + wsumS[r * 4 + 3];
                acc2 += M + logf(S) - shDS[r];
            }
            spar[blockIdx.x] = acc2;
        }
    }
}

// ---------------- fixup (128 blocks) + last-block final (hist/perplexity/spar) ----------------
__global__ __launch_bounds__(256)
void vq_fixup_final(const float* __restrict__ z, const float* __restrict__ emb,
                    const float* __restrict__ re, int* __restrict__ cnt,
                    const int* __restrict__ flags, float* __restrict__ out,
                    float* __restrict__ scal, int* __restrict__ idx,
                    const float* __restrict__ spar) {
    __shared__ __align__(16) float zs[8][ZD];
    __shared__ u64 sb[4][8];
    __shared__ int nwS[8];
    __shared__ float addS;
    __shared__ int   histL[1024];
    __shared__ float red[256];
    __shared__ int ticketL;

    const int tid = threadIdx.x;
    const int w   = tid >> 6;
    const int lane = tid & 63;
    int n = cnt[0];
    if (n > FLAGCAP) n = FLAGCAP;

    for (int base = blockIdx.x * 8; base < n; base += 128 * 8) {
        const int nr = (n - base < 8) ? (n - base) : 8;
        __syncthreads();
        for (int i = tid; i < nr * 256; i += 256) {
            const int r = i >> 8, k = i & 255;
            const int rowg = flags[base + r] & 0xFFFF;
            zs[r][k] = z[(size_t)(rowg >> 12) * ZD * TT + (size_t)k * TT + (rowg & 4095)];
        }
        __syncthreads();

        u64 best[8];
        #pragma unroll
        for (int r = 0; r < 8; ++r) best[r] = 0xFFFFFFFFFFFFFFFFull;

        for (int cc = 0; cc < 4; ++cc) {
            const int c = cc * 256 + tid;
            const float4* ec = (const float4*)(emb + (size_t)c * ZD);
            float a[8] = {0.f,0.f,0.f,0.f,0.f,0.f,0.f,0.f};
            for (int k4 = 0; k4 < ZD / 4; ++k4) {
                float4 e4 = ec[k4];
                #pragma unroll
                for (int r = 0; r < 8; ++r) {
                    const float* a4 = &zs[r][k4 * 4];
                    a[r] = fmaf(e4.x, a4[0], fmaf(e4.y, a4[1],
                           fmaf(e4.z, a4[2], fmaf(e4.w, a4[3], a[r]))));
                }
            }
            const float rc = re[c];
            #pragma unroll
            for (int r = 0; r < 8; ++r) {
                if (r < nr) {
                    float s = fmaf(-2.f, a[r], rc);
                    u64 pk = ((u64)flip32(s) << 32) | (u32)c;
                    if (pk < best[r]) best[r] = pk;
                }
            }
        }
        #pragma unroll
        for (int r = 0; r < 8; ++r) {
            if (r < nr) {
                u64 bv = best[r];
                #pragma unroll
                for (int off = 32; off; off >>= 1) {
                    u64 o = (u64)__shfl_xor((long long)bv, off, 64);
                    if (o < bv) bv = o;
                }
                if (lane == 0) sb[w][r] = bv;
            }
        }
        __syncthreads();
        if (tid == 0) addS = 0.f;
        __syncthreads();
        if (tid < nr) {
            u64 m = sb[0][tid];
            if (sb[1][tid] < m) m = sb[1][tid];
            if (sb[2][tid] < m) m = sb[2][tid];
            if (sb[3][tid] < m) m = sb[3][tid];
            const int nc  = (int)(u32)(m & 0xFFFFFFFFull);
            const float s = unflip32((u32)(m >> 32));
            const int rowg = flags[base + tid] & 0xFFFF;
            const int old  = (flags[base + tid] >> 16) & 1023;
            atomicAdd(&addS, s);
            if (nc != old) { idx[rowg] = nc; nwS[tid] = nc; }
            else nwS[tid] = -1;
        }
        __syncthreads();
        if (tid == 0) { atomicAdd(scal + 0, addS); atomicAdd(scal + 1, addS); }
        for (int r = 0; r < nr; ++r) {
            const int nw = nwS[r];
            if (nw >= 0) {
                const int rowg = flags[base + r] & 0xFFFF;
                out[(size_t)(rowg >> 12) * ZD * TT + (size_t)tid * TT + (rowg & 4095)]
                    = emb[(size_t)nw * ZD + tid];
            }
        }
    }

    // ---- device-scope ticket: last block does the final reductions ----
    __syncthreads();
    __threadfence();
    if (tid == 0) ticketL = atomicAdd(&cnt[1], 1);
    __syncthreads();
    if (ticketL != 127) return;
    __threadfence();    // acquire: all other blocks' idx/scal writes visible

    // histogram from corrected idx (coalesced reads, LDS atomics)
    histL[tid] = 0; histL[256 + tid] = 0; histL[512 + tid] = 0; histL[768 + tid] = 0;
    __syncthreads();
    for (int i = 0; i < 256; ++i)
        atomicAdd(&histL[idx[i * 256 + tid]], 1);
    __syncthreads();
    float s = 0.f;
    #pragma unroll
    for (int j = 0; j < 4; ++j) {
        float p = (float)histL[j * 256 + tid] * (1.0f / (float)NROWS);
        s -= p * logf(p + 1e-10f);
    }
    red[tid] = s;
    __syncthreads();
    for (int st = 128; st; st >>= 1) {
        if (tid < st) red[tid] += red[tid + st];
        __syncthreads();
    }
    if (tid == 0) scal[2] = expf(red[0]);
    __syncthreads();
    red[tid] = spar[tid] + spar[256 + tid];
    __syncthreads();
    for (int st = 128; st; st >>= 1) {
        if (tid < st) red[tid] += red[tid + st];
        __syncthreads();
    }
    if (tid == 0) scal[3] = red[0] * (1.0f / (float)KC);
}

extern "C" void kernel_launch(void* const* d_in, const int* in_sizes, int n_in,
                              void* d_out, int out_size, void* d_ws, size_t ws_size,
                              hipStream_t stream) {
    const float* z   = (const float*)d_in[0];
    const float* emb = (const float*)d_in[1];
    float* out = (float*)d_out;
    const size_t NOUT = (size_t)BB * ZD * TT;    // 16777216
    float* scal = out + NOUT;                    // [qut, enc, perp, sparsity]

    float* re    = (float*)d_ws;                 // 1024 f32
    int*   cnt   = (int*)(re + KC);              // 4 i32 (cnt, done)
    int*   flags = cnt + 4;                      // FLAGCAP i32
    float* spar  = (float*)(flags + FLAGCAP);    // 512 f32
    int*   idx   = (int*)(spar + 512);           // 65536 i32
    _Float16* eh = (_Float16*)(idx + NROWS);     // 1024*256 f16

    vq_prep_kernel<<<256, 256, 0, stream>>>(emb, eh, re, cnt, scal);
    vq_argmin_mfma<<<NROWS / 128, 256, 0, stream>>>(z, eh, emb, re, out, scal, idx,
                                                    cnt, flags, spar);
    vq_fixup_final<<<128, 256, 0, stream>>>(z, emb, re, cnt, flags, out, scal, idx, spar);
}

// Round 17
// 226.552 us; speedup vs baseline: 1.2955x; 1.2955x over previous
//
#include <hip/hip_runtime.h>
#include <math.h>

typedef unsigned int u32;
typedef unsigned long long u64;
typedef _Float16 f16x8 __attribute__((ext_vector_type(8)));
typedef _Float16 f16x4 __attribute__((ext_vector_type(4)));
typedef float f32x4 __attribute__((ext_vector_type(4)));
typedef __attribute__((address_space(1))) const char gch;
typedef __attribute__((address_space(3))) char lch;

#define ZD 256      // z_dim (C)
#define KC 1024     // number of codes
#define TT 4096     // T
#define BB 16       // B
#define NROWS (BB*TT)     // 65536
#define TAU 0.12f         // margin threshold (~6 sigma of fp16 pairwise err)
#define FLAGCAP 32768

__device__ __forceinline__ u32 flip32(float s) {
    int i = __float_as_int(s);
    return (u32)(i ^ ((i >> 31) | 0x80000000));
}
__device__ __forceinline__ float unflip32(u32 u) {
    int m = (~(((int)u) >> 31)) | 0x80000000;
    return __int_as_float((int)(u ^ (u32)m));
}

// ---------------- prep: zero cnt/ticket, re=||e||^2, emb->fp16 ----------------
__global__ __launch_bounds__(256)
void vq_prep_kernel(const float* __restrict__ emb, _Float16* __restrict__ eh,
                    float* __restrict__ re, int* __restrict__ cnt) {
    int gid = blockIdx.x * 256 + threadIdx.x;
    if (gid < 2) cnt[gid] = 0;      // cnt[0]=flag count, cnt[1]=done ticket

    int code = gid >> 6;   // one wave per code
    int lane = threadIdx.x & 63;
    float4 v = *(const float4*)(emb + (size_t)code * ZD + lane * 4);
    float s = v.x*v.x + v.y*v.y + v.z*v.z + v.w*v.w;
    #pragma unroll
    for (int off = 32; off; off >>= 1) s += __shfl_down(s, off, 64);
    if (lane == 0) re[code] = s;

    f16x4 hv;
    hv[0] = (_Float16)v.x; hv[1] = (_Float16)v.y;
    hv[2] = (_Float16)v.z; hv[3] = (_Float16)v.w;
    *(f16x4*)(eh + (size_t)code * ZD + lane * 4) = hv;
}

// ---- stage one 32-code half-tile (16KB) via global_load_lds; 4 waves x 4 loads ----
__device__ __forceinline__ void stage_half4(const char* ehc, char* dstbase,
                                            int h, int w, int l) {
    const int srow = h * 16384;             // 32 codes * 512B
    #pragma unroll
    for (int j = 0; j < 4; ++j) {
        const int gi  = w * 4 + j;          // 0..15
        const int c   = 2 * gi + (l >> 5);  // local code this lane's 16B lands in
        const int kbs = (l & 31) * 16;
        const int off = srow + c * 512 + (kbs ^ ((c & 7) << 4));
        __builtin_amdgcn_global_load_lds((gch*)(ehc + off),
                                         (lch*)(dstbase + gi * 1024), 16, 0, 0);
    }
}

// ---- one 32-code compute phase: 16 ds_read_b128 + 32 MFMA (2 rowgroups) ----
__device__ __forceinline__ void compute_phase32(const char* hb, int h,
                                                const f16x8 (&ah)[2][8], const float* reL,
                                                float (&v1)[8], float (&v2)[8], int (&i1)[8],
                                                int lane15, int lk) {
    #pragma unroll
    for (int cg = 0; cg < 2; ++cg) {
        const int c  = cg * 16 + lane15;        // local code 0..31
        const int sw = (lane15 & 7) << 4;       // c&7 == lane15&7
        f16x8 bh[8];
        #pragma unroll
        for (int ks = 0; ks < 8; ++ks)
            bh[ks] = *(const f16x8*)(hb + c * 512 + ((lk * 16 + ks * 64) ^ sw));

        f32x4 a0 = {0.f, 0.f, 0.f, 0.f};
        f32x4 a1 = {0.f, 0.f, 0.f, 0.f};
        __builtin_amdgcn_s_setprio(1);
        #pragma unroll
        for (int ks = 0; ks < 8; ++ks) {
            a0 = __builtin_amdgcn_mfma_f32_16x16x32_f16(ah[0][ks], bh[ks], a0, 0, 0, 0);
            a1 = __builtin_amdgcn_mfma_f32_16x16x32_f16(ah[1][ks], bh[ks], a1, 0, 0, 0);
        }
        __builtin_amdgcn_s_setprio(0);

        const int codeg = h * 32 + c;
        const float rc = reL[codeg];
        #pragma unroll
        for (int r = 0; r < 4; ++r) {
            float s0 = fmaf(-2.f, a0[r], rc);
            float n2a = fminf(fmaxf(v1[r], s0), v2[r]);          // med3(v1,v2,s0)
            i1[r] = (s0 < v1[r]) ? codeg : i1[r];
            v1[r] = fminf(v1[r], s0);
            v2[r] = n2a;
            float s1 = fmaf(-2.f, a1[r], rc);
            float n2b = fminf(fmaxf(v1[4 + r], s1), v2[4 + r]);
            i1[4 + r] = (s1 < v1[4 + r]) ? codeg : i1[4 + r];
            v1[4 + r] = fminf(v1[4 + r], s1);
            v2[4 + r] = n2b;
        }
    }
}

// ---------------- fused argmin + out-write + loss partial + idx ----------------
// 512 blocks x 256 threads (4 waves). Block: 128 rows; wave w: rows [32w,32w+32).
// z staged coalesced via global_load_lds; 32 phases, ring-4 LDS, counted vmcnt(8).
// Loss emitted as per-block partial lossP[bid] (no same-address atomics).
__global__ __launch_bounds__(256, 2)
void vq_argmin_mfma(const float* __restrict__ z, const _Float16* __restrict__ eh,
                    const float* __restrict__ emb, const float* __restrict__ re,
                    float* __restrict__ out, float* __restrict__ lossP,
                    int* __restrict__ idx, int* __restrict__ cnt,
                    int* __restrict__ flags) {
    __shared__ __align__(16) char lds[71168];   // ring 4x16KB | reL 4KB | tails
    float* reL   = (float*)(lds + 65536);   // 1024 f32
    float* zsqL  = (float*)(lds + 69632);   // 128 f32 (reused as wave-loss scratch)
    int*   idsL  = (int*)  (lds + 70144);   // 128 i32
    float* lossL = (float*)(lds + 70656);   // 128 f32

    const int tid = threadIdx.x;
    const int w   = tid >> 6;       // 0..3
    const int l   = tid & 63;
    const int lane15 = l & 15;
    const int lk     = l >> 4;
    const int r0  = blockIdx.x * 128;
    const int b   = r0 >> 12;
    const int t0  = r0 & 4095;
    const char* ehc = (const char*)eh;

    *(float4*)(reL + tid * 4) = *(const float4*)(re + tid * 4);

    // ---- z prologue: coalesced glds staging into ring[w] (16KB), 2 rounds of 128 c ----
    f16x8 ah[2][8];
    float zsq[2] = {0.f, 0.f};
    {
        const char* zb = (const char*)(z + (size_t)b * ZD * TT + t0 + w * 32);
        char* zdst = lds + w * 16384;
        #pragma unroll
        for (int round = 0; round < 2; ++round) {
            #pragma unroll
            for (int j = 0; j < 16; ++j) {
                const int c  = round * 128 + j * 8 + (l >> 3);
                const int tb = (l & 7) * 16;
                const char* src = zb + (size_t)c * TT * 4 + tb;
                __builtin_amdgcn_global_load_lds((gch*)src, (lch*)(zdst + j * 1024),
                                                 16, 0, 0);
            }
            asm volatile("s_waitcnt vmcnt(0)" ::: "memory");
            __builtin_amdgcn_sched_barrier(0);
            #pragma unroll
            for (int rg = 0; rg < 2; ++rg) {
                const int tw = rg * 16 + lane15;
                #pragma unroll
                for (int ks2 = 0; ks2 < 4; ++ks2) {
                    const int cl = ks2 * 32 + lk * 8;   // local c within round
                    f16x8 h;
                    #pragma unroll
                    for (int j = 0; j < 8; ++j) {
                        float v = *(const float*)(zdst + (cl + j) * 128 + tw * 4);
                        zsq[rg] = fmaf(v, v, zsq[rg]);
                        h[j] = (_Float16)v;
                    }
                    ah[rg][round * 4 + ks2] = h;
                }
            }
            asm volatile("s_waitcnt lgkmcnt(0)" ::: "memory");  // reads done before reuse
            __builtin_amdgcn_sched_barrier(0);
        }
    }
    #pragma unroll
    for (int rg = 0; rg < 2; ++rg) {
        zsq[rg] += __shfl_xor(zsq[rg], 16, 64);
        zsq[rg] += __shfl_xor(zsq[rg], 32, 64);
        if (l < 16) zsqL[w * 32 + rg * 16 + l] = zsq[rg];
    }

    float v1[8], v2[8];
    int   i1[8];
    #pragma unroll
    for (int s8 = 0; s8 < 8; ++s8) { v1[s8] = 3.4e38f; v2[s8] = 3.4e38f; i1[s8] = 0; }

    // all waves done using ring as z-scratch; drain ds ops, then begin e-staging
    asm volatile("s_waitcnt vmcnt(0) lgkmcnt(0)" ::: "memory");
    __syncthreads();
    stage_half4(ehc, lds,         0, w, l);
    stage_half4(ehc, lds + 16384, 1, w, l);
    stage_half4(ehc, lds + 32768, 2, w, l);

    // Phase h reads buf[h&3]; stage(h+3) (issued after the phase-h barrier) writes
    // buf[(h-1)&3], whose reads finished at that barrier. At the wait, stages h+1
    // and h+2 are outstanding (4 loads each) -> vmcnt(8) guarantees stage h landed.
    for (int h = 0; h < 30; ++h) {
        asm volatile("s_waitcnt vmcnt(8)" ::: "memory");
        __builtin_amdgcn_sched_barrier(0);
        __builtin_amdgcn_s_barrier();
        if (h < 29) stage_half4(ehc, lds + ((h + 3) & 3) * 16384, h + 3, w, l);
        compute_phase32(lds + (h & 3) * 16384, h, ah, reL, v1, v2, i1, lane15, lk);
    }
    asm volatile("s_waitcnt vmcnt(4)" ::: "memory");
    __builtin_amdgcn_sched_barrier(0);
    __builtin_amdgcn_s_barrier();
    compute_phase32(lds + (30 & 3) * 16384, 30, ah, reL, v1, v2, i1, lane15, lk);
    asm volatile("s_waitcnt vmcnt(0)" ::: "memory");
    __builtin_amdgcn_sched_barrier(0);
    __builtin_amdgcn_s_barrier();
    compute_phase32(lds + (31 & 3) * 16384, 31, ah, reL, v1, v2, i1, lane15, lk);

    // reduce across the 16 lanes holding different codes (same rows)
    #pragma unroll
    for (int off = 1; off < 16; off <<= 1) {
        #pragma unroll
        for (int s8 = 0; s8 < 8; ++s8) {
            float ov1 = __shfl_xor(v1[s8], off, 64);
            int   oi1 = __shfl_xor(i1[s8], off, 64);
            float ov2 = __shfl_xor(v2[s8], off, 64);
            float nv2 = fminf(fmaxf(v1[s8], ov1), fminf(v2[s8], ov2));
            if (ov1 < v1[s8] || (ov1 == v1[s8] && oi1 < i1[s8])) { v1[s8] = ov1; i1[s8] = oi1; }
            v2[s8] = nv2;
        }
    }
    if (lane15 == 0) {
        #pragma unroll
        for (int s8 = 0; s8 < 8; ++s8) {
            const int rg = s8 >> 2, rr = s8 & 3;
            const int row = w * 32 + rg * 16 + lk * 4 + rr;   // local row 0..127
            idsL[row] = i1[s8];
            const bool fl = (v2[s8] - v1[s8] < TAU);
            lossL[row] = fl ? zsqL[row] : (zsqL[row] + v1[s8]);
            if (fl) {
                int p = atomicAdd(cnt, 1);
                if (p < FLAGCAP) flags[p] = (r0 + row) | (i1[s8] << 16);
            }
        }
    }
    __syncthreads();

    // idx store (coalesced) + block loss partial (zsqL reused as 2-slot scratch)
    if (tid < 128) {
        idx[r0 + tid] = idsL[tid];
        float lv = lossL[tid];
        #pragma unroll
        for (int off = 32; off; off >>= 1) lv += __shfl_down(lv, off, 64);
        if (l == 0) zsqL[tid >> 6] = lv;
    }
    __syncthreads();
    if (tid == 0) lossP[blockIdx.x] = zsqL[0] + zsqL[1];

    // out-write: wave w covers c in [64w, 64w+64), all 128 rows
    {
        const int c0 = w * 64;
        float* ob = out + (size_t)b * ZD * TT + t0;
        #pragma unroll
        for (int half = 0; half < 2; ++half) {
            const int tt = half * 64 + l;
            const int ii = idsL[tt];
            const float4* er4 = (const float4*)(emb + (size_t)ii * ZD + c0);
            #pragma unroll
            for (int c4 = 0; c4 < 16; ++c4) {
                float4 ev = er4[c4];
                float* o0 = ob + (size_t)(c0 + c4 * 4) * TT + tt;
                o0[0]      = ev.x;
                o0[TT]     = ev.y;
                o0[2 * TT] = ev.z;
                o0[3 * TT] = ev.w;
            }
        }
    }
}

// ------- fixup (blocks 0..127) + sparsity (blocks 128..255) + last-block final -------
__global__ __launch_bounds__(256)
void vq_fixup_spar(const float* __restrict__ z, const float* __restrict__ emb,
                   const float* __restrict__ re, int* __restrict__ cnt,
                   const int* __restrict__ flags, float* __restrict__ out,
                   float* __restrict__ scal, int* __restrict__ idx,
                   float* __restrict__ spar, float* __restrict__ lossP,
                   float* __restrict__ addP) {
    __shared__ __align__(16) float zs[8][ZD];
    __shared__ u64 sb[4][8];
    __shared__ int nwS[8];
    __shared__ float addS;
    __shared__ __align__(16) float er[8][260];
    __shared__ float wmaxS[8][4];
    __shared__ float wsumS[8][4];
    __shared__ float shD[8];
    __shared__ int   histL[1024];
    __shared__ float red[256];
    __shared__ int ticketL;

    const int tid = threadIdx.x;
    const int w   = tid >> 6;
    const int lane = tid & 63;

    if (blockIdx.x >= 128) {
        // ---- sparsity: 8 rows/block, partial to spar[bid2] ----
        const int bid2 = blockIdx.x - 128;      // 0..127
        const int r0   = bid2 * 8;

        for (int i = tid; i < 8 * 256; i += 256) er[i >> 8][i & 255] = emb[(size_t)r0 * ZD + i];
        __syncthreads();

        float dots[4][8];
        #pragma unroll
        for (int cc = 0; cc < 4; ++cc) {
            const int c = cc * 256 + tid;
            const float4* ec = (const float4*)(emb + (size_t)c * ZD);
            float a[8] = {0.f,0.f,0.f,0.f,0.f,0.f,0.f,0.f};
            for (int k4 = 0; k4 < ZD / 4; ++k4) {
                float4 e4 = ec[k4];
                #pragma unroll
                for (int r = 0; r < 8; ++r) {
                    const float* a4 = &er[r][k4 * 4];
                    a[r] = fmaf(e4.x, a4[0], fmaf(e4.y, a4[1],
                           fmaf(e4.z, a4[2], fmaf(e4.w, a4[3], a[r]))));
                }
            }
            #pragma unroll
            for (int r = 0; r < 8; ++r) dots[cc][r] = a[r];
            const int gr = c - r0;
            if (gr >= 0 && gr < 8) shD[gr] = a[gr];
        }
        #pragma unroll
        for (int r = 0; r < 8; ++r) {
            float m = fmaxf(fmaxf(dots[0][r], dots[1][r]), fmaxf(dots[2][r], dots[3][r]));
            #pragma unroll
            for (int off = 32; off; off >>= 1) m = fmaxf(m, __shfl_xor(m, off, 64));
            if (lane == 0) wmaxS[r][w] = m;
        }
        __syncthreads();
        #pragma unroll
        for (int r = 0; r < 8; ++r) {
            const float M = fmaxf(fmaxf(wmaxS[r][0], wmaxS[r][1]),
                                  fmaxf(wmaxS[r][2], wmaxS[r][3]));
            float se = expf(dots[0][r] - M) + expf(dots[1][r] - M)
                     + expf(dots[2][r] - M) + expf(dots[3][r] - M);
            #pragma unroll
            for (int off = 32; off; off >>= 1) se += __shfl_xor(se, off, 64);
            if (lane == 0) wsumS[r][w] = se;
        }
        __syncthreads();
        if (tid == 0) {
            float acc = 0.f;
            #pragma unroll
            for (int r = 0; r < 8; ++r) {
                const float M = fmaxf(fmaxf(wmaxS[r][0], wmaxS[r][1]),
                                      fmaxf(wmaxS[r][2], wmaxS[r][3]));
                const float S = wsumS[r][0] + wsumS[r][1] + wsumS[r][2] + wsumS[r][3];
                acc += M + logf(S) - shD[r];
            }
            spar[bid2] = acc;
        }
    } else {
        // ---- fixup: exact fp32 rescore, 8 flagged rows per pass, 128 blocks ----
        int n = cnt[0];
        if (n > FLAGCAP) n = FLAGCAP;
        float blkLoss = 0.f;    // meaningful at tid==0 only

        for (int base = blockIdx.x * 8; base < n; base += 128 * 8) {
            const int nr = (n - base < 8) ? (n - base) : 8;
            __syncthreads();
            for (int i = tid; i < nr * 256; i += 256) {
                const int r = i >> 8, k = i & 255;
                const int rowg = flags[base + r] & 0xFFFF;
                zs[r][k] = z[(size_t)(rowg >> 12) * ZD * TT + (size_t)k * TT + (rowg & 4095)];
            }
            __syncthreads();

            u64 best[8];
            #pragma unroll
            for (int r = 0; r < 8; ++r) best[r] = 0xFFFFFFFFFFFFFFFFull;

            for (int cc = 0; cc < 4; ++cc) {
                const int c = cc * 256 + tid;
                const float4* ec = (const float4*)(emb + (size_t)c * ZD);
                float a[8] = {0.f,0.f,0.f,0.f,0.f,0.f,0.f,0.f};
                for (int k4 = 0; k4 < ZD / 4; ++k4) {
                    float4 e4 = ec[k4];
                    #pragma unroll
                    for (int r = 0; r < 8; ++r) {
                        const float* a4 = &zs[r][k4 * 4];
                        a[r] = fmaf(e4.x, a4[0], fmaf(e4.y, a4[1],
                               fmaf(e4.z, a4[2], fmaf(e4.w, a4[3], a[r]))));
                    }
                }
                const float rc = re[c];
                #pragma unroll
                for (int r = 0; r < 8; ++r) {
                    if (r < nr) {
                        float s = fmaf(-2.f, a[r], rc);
                        u64 pk = ((u64)flip32(s) << 32) | (u32)c;
                        if (pk < best[r]) best[r] = pk;
                    }
                }
            }
            #pragma unroll
            for (int r = 0; r < 8; ++r) {
                if (r < nr) {
                    u64 bv = best[r];
                    #pragma unroll
                    for (int off = 32; off; off >>= 1) {
                        u64 o = (u64)__shfl_xor((long long)bv, off, 64);
                        if (o < bv) bv = o;
                    }
                    if (lane == 0) sb[w][r] = bv;
                }
            }
            __syncthreads();
            if (tid == 0) addS = 0.f;
            __syncthreads();
            if (tid < nr) {
                u64 m = sb[0][tid];
                if (sb[1][tid] < m) m = sb[1][tid];
                if (sb[2][tid] < m) m = sb[2][tid];
                if (sb[3][tid] < m) m = sb[3][tid];
                const int nc  = (int)(u32)(m & 0xFFFFFFFFull);
                const float s = unflip32((u32)(m >> 32));
                const int rowg = flags[base + tid] & 0xFFFF;
                const int old  = (flags[base + tid] >> 16) & 1023;
                atomicAdd(&addS, s);
                if (nc != old) { idx[rowg] = nc; nwS[tid] = nc; }
                else nwS[tid] = -1;
            }
            __syncthreads();
            if (tid == 0) blkLoss += addS;
            for (int r = 0; r < nr; ++r) {
                const int nw = nwS[r];
                if (nw >= 0) {
                    const int rowg = flags[base + r] & 0xFFFF;
                    out[(size_t)(rowg >> 12) * ZD * TT + (size_t)tid * TT + (rowg & 4095)]
                        = emb[(size_t)nw * ZD + tid];
                }
            }
        }
        if (tid == 0) addP[blockIdx.x] = blkLoss;
    }

    // ---- device-scope ticket: last of the 256 blocks does the final reductions ----
    __syncthreads();
    __threadfence();
    if (tid == 0) ticketL = atomicAdd(&cnt[1], 1);
    __syncthreads();
    if (ticketL != 255) return;
    __threadfence();    // acquire: all other blocks' idx/spar/lossP/addP writes visible

    // histogram from corrected idx (coalesced reads, LDS atomics)
    #pragma unroll
    for (int j = 0; j < 4; ++j) histL[j * 256 + tid] = 0;
    __syncthreads();
    #pragma unroll 8
    for (int i = 0; i < 256; ++i)
        atomicAdd(&histL[idx[i * 256 + tid]], 1);
    __syncthreads();
    float s = 0.f;
    #pragma unroll
    for (int j = 0; j < 4; ++j) {
        float p = (float)histL[j * 256 + tid] * (1.0f / (float)NROWS);
        s -= p * logf(p + 1e-10f);
    }
    red[tid] = s;
    __syncthreads();
    for (int st = 128; st; st >>= 1) {
        if (tid < st) red[tid] += red[tid + st];
        __syncthreads();
    }
    if (tid == 0) scal[2] = expf(red[0]);
    __syncthreads();

    // loss: sum of 512 argmin partials + 128 fixup partials
    red[tid] = lossP[tid] + lossP[256 + tid] + ((tid < 128) ? addP[tid] : 0.f);
    __syncthreads();
    for (int st = 128; st; st >>= 1) {
        if (tid < st) red[tid] += red[tid + st];
        __syncthreads();
    }
    if (tid == 0) { scal[0] = red[0]; scal[1] = red[0]; }
    __syncthreads();

    // sparsity: sum of 128 partials
    red[tid] = (tid < 128) ? spar[tid] : 0.f;
    __syncthreads();
    for (int st = 128; st; st >>= 1) {
        if (tid < st) red[tid] += red[tid + st];
        __syncthreads();
    }
    if (tid == 0) scal[3] = red[0] * (1.0f / (float)KC);
}

extern "C" void kernel_launch(void* const* d_in, const int* in_sizes, int n_in,
                              void* d_out, int out_size, void* d_ws, size_t ws_size,
                              hipStream_t stream) {
    const float* z   = (const float*)d_in[0];
    const float* emb = (const float*)d_in[1];
    float* out = (float*)d_out;
    const size_t NOUT = (size_t)BB * ZD * TT;    // 16777216
    float* scal = out + NOUT;                    // [qut, enc, perp, sparsity]

    float* re    = (float*)d_ws;                 // 1024 f32
    int*   cnt   = (int*)(re + KC);              // 4 i32 (flag count, ticket)
    int*   flags = cnt + 4;                      // FLAGCAP i32
    float* spar  = (float*)(flags + FLAGCAP);    // 128 f32
    float* lossP = spar + 128;                   // 512 f32
    float* addP  = lossP + 512;                  // 128 f32
    int*   idx   = (int*)(addP + 128);           // 65536 i32
    _Float16* eh = (_Float16*)(idx + NROWS);     // 1024*256 f16

    vq_prep_kernel<<<256, 256, 0, stream>>>(emb, eh, re, cnt);
    vq_argmin_mfma<<<NROWS / 128, 256, 0, stream>>>(z, eh, emb, re, out, lossP, idx,
                                                    cnt, flags);
    vq_fixup_spar<<<256, 256, 0, stream>>>(z, emb, re, cnt, flags, out, scal, idx,
                                           spar, lossP, addP);
}

// Round 18
// 212.982 us; speedup vs baseline: 1.3780x; 1.0637x over previous
//
#include <hip/hip_runtime.h>
#include <math.h>

typedef unsigned int u32;
typedef unsigned long long u64;
typedef _Float16 f16x8 __attribute__((ext_vector_type(8)));
typedef _Float16 f16x4 __attribute__((ext_vector_type(4)));
typedef float f32x4 __attribute__((ext_vector_type(4)));
typedef __attribute__((address_space(1))) const char gch;
typedef __attribute__((address_space(3))) char lch;

#define ZD 256      // z_dim (C)
#define KC 1024     // number of codes
#define TT 4096     // T
#define BB 16       // B
#define NROWS (BB*TT)     // 65536
#define TAU 0.12f         // margin threshold (~6 sigma of fp16 pairwise err)
#define FLAGCAP 32768

__device__ __forceinline__ u32 flip32(float s) {
    int i = __float_as_int(s);
    return (u32)(i ^ ((i >> 31) | 0x80000000));
}
__device__ __forceinline__ float unflip32(u32 u) {
    int m = (~(((int)u) >> 31)) | 0x80000000;
    return __int_as_float((int)(u ^ (u32)m));
}

// ---------------- prep: zero cnt, re=||e||^2, emb->fp16 ----------------
__global__ __launch_bounds__(256)
void vq_prep_kernel(const float* __restrict__ emb, _Float16* __restrict__ eh,
                    float* __restrict__ re, int* __restrict__ cnt) {
    int gid = blockIdx.x * 256 + threadIdx.x;
    if (gid < 2) cnt[gid] = 0;      // cnt[0]=flag count

    int code = gid >> 6;   // one wave per code
    int lane = threadIdx.x & 63;
    float4 v = *(const float4*)(emb + (size_t)code * ZD + lane * 4);
    float s = v.x*v.x + v.y*v.y + v.z*v.z + v.w*v.w;
    #pragma unroll
    for (int off = 32; off; off >>= 1) s += __shfl_down(s, off, 64);
    if (lane == 0) re[code] = s;

    f16x4 hv;
    hv[0] = (_Float16)v.x; hv[1] = (_Float16)v.y;
    hv[2] = (_Float16)v.z; hv[3] = (_Float16)v.w;
    *(f16x4*)(eh + (size_t)code * ZD + lane * 4) = hv;
}

// ---- stage one 32-code half-tile (16KB) via global_load_lds; 4 waves x 4 loads ----
__device__ __forceinline__ void stage_half4(const char* ehc, char* dstbase,
                                            int h, int w, int l) {
    const int srow = h * 16384;             // 32 codes * 512B
    #pragma unroll
    for (int j = 0; j < 4; ++j) {
        const int gi  = w * 4 + j;          // 0..15
        const int c   = 2 * gi + (l >> 5);  // local code this lane's 16B lands in
        const int kbs = (l & 31) * 16;
        const int off = srow + c * 512 + (kbs ^ ((c & 7) << 4));
        __builtin_amdgcn_global_load_lds((gch*)(ehc + off),
                                         (lch*)(dstbase + gi * 1024), 16, 0, 0);
    }
}

// ---- one 32-code compute phase: 16 ds_read_b128 + 32 MFMA (2 rowgroups) ----
__device__ __forceinline__ void compute_phase32(const char* hb, int h,
                                                const f16x8 (&ah)[2][8], const float* reL,
                                                float (&v1)[8], float (&v2)[8], int (&i1)[8],
                                                int lane15, int lk) {
    #pragma unroll
    for (int cg = 0; cg < 2; ++cg) {
        const int c  = cg * 16 + lane15;        // local code 0..31
        const int sw = (lane15 & 7) << 4;       // c&7 == lane15&7
        f16x8 bh[8];
        #pragma unroll
        for (int ks = 0; ks < 8; ++ks)
            bh[ks] = *(const f16x8*)(hb + c * 512 + ((lk * 16 + ks * 64) ^ sw));

        f32x4 a0 = {0.f, 0.f, 0.f, 0.f};
        f32x4 a1 = {0.f, 0.f, 0.f, 0.f};
        __builtin_amdgcn_s_setprio(1);
        #pragma unroll
        for (int ks = 0; ks < 8; ++ks) {
            a0 = __builtin_amdgcn_mfma_f32_16x16x32_f16(ah[0][ks], bh[ks], a0, 0, 0, 0);
            a1 = __builtin_amdgcn_mfma_f32_16x16x32_f16(ah[1][ks], bh[ks], a1, 0, 0, 0);
        }
        __builtin_amdgcn_s_setprio(0);

        const int codeg = h * 32 + c;
        const float rc = reL[codeg];
        #pragma unroll
        for (int r = 0; r < 4; ++r) {
            float s0 = fmaf(-2.f, a0[r], rc);
            float n2a = fminf(fmaxf(v1[r], s0), v2[r]);          // med3(v1,v2,s0)
            i1[r] = (s0 < v1[r]) ? codeg : i1[r];
            v1[r] = fminf(v1[r], s0);
            v2[r] = n2a;
            float s1 = fmaf(-2.f, a1[r], rc);
            float n2b = fminf(fmaxf(v1[4 + r], s1), v2[4 + r]);
            i1[4 + r] = (s1 < v1[4 + r]) ? codeg : i1[4 + r];
            v1[4 + r] = fminf(v1[4 + r], s1);
            v2[4 + r] = n2b;
        }
    }
}

// ---------------- fused argmin + out-write + loss partial + idx ----------------
// 512 blocks x 256 threads (4 waves). Block: 128 rows; wave w: rows [32w,32w+32).
// z staged coalesced via global_load_lds; 32 phases, ring-4 LDS, counted vmcnt(8).
// Loss emitted as per-block partial lossP[bid] (no same-address atomics).
__global__ __launch_bounds__(256, 2)
void vq_argmin_mfma(const float* __restrict__ z, const _Float16* __restrict__ eh,
                    const float* __restrict__ emb, const float* __restrict__ re,
                    float* __restrict__ out, float* __restrict__ lossP,
                    int* __restrict__ idx, int* __restrict__ cnt,
                    int* __restrict__ flags) {
    __shared__ __align__(16) char lds[71168];   // ring 4x16KB | reL 4KB | tails
    float* reL   = (float*)(lds + 65536);   // 1024 f32
    float* zsqL  = (float*)(lds + 69632);   // 128 f32 (reused as wave-loss scratch)
    int*   idsL  = (int*)  (lds + 70144);   // 128 i32
    float* lossL = (float*)(lds + 70656);   // 128 f32

    const int tid = threadIdx.x;
    const int w   = tid >> 6;       // 0..3
    const int l   = tid & 63;
    const int lane15 = l & 15;
    const int lk     = l >> 4;
    const int r0  = blockIdx.x * 128;
    const int b   = r0 >> 12;
    const int t0  = r0 & 4095;
    const char* ehc = (const char*)eh;

    *(float4*)(reL + tid * 4) = *(const float4*)(re + tid * 4);

    // ---- z prologue: coalesced glds staging into ring[w] (16KB), 2 rounds of 128 c ----
    f16x8 ah[2][8];
    float zsq[2] = {0.f, 0.f};
    {
        const char* zb = (const char*)(z + (size_t)b * ZD * TT + t0 + w * 32);
        char* zdst = lds + w * 16384;
        #pragma unroll
        for (int round = 0; round < 2; ++round) {
            #pragma unroll
            for (int j = 0; j < 16; ++j) {
                const int c  = round * 128 + j * 8 + (l >> 3);
                const int tb = (l & 7) * 16;
                const char* src = zb + (size_t)c * TT * 4 + tb;
                __builtin_amdgcn_global_load_lds((gch*)src, (lch*)(zdst + j * 1024),
                                                 16, 0, 0);
            }
            asm volatile("s_waitcnt vmcnt(0)" ::: "memory");
            __builtin_amdgcn_sched_barrier(0);
            #pragma unroll
            for (int rg = 0; rg < 2; ++rg) {
                const int tw = rg * 16 + lane15;
                #pragma unroll
                for (int ks2 = 0; ks2 < 4; ++ks2) {
                    const int cl = ks2 * 32 + lk * 8;   // local c within round
                    f16x8 h;
                    #pragma unroll
                    for (int j = 0; j < 8; ++j) {
                        float v = *(const float*)(zdst + (cl + j) * 128 + tw * 4);
                        zsq[rg] = fmaf(v, v, zsq[rg]);
                        h[j] = (_Float16)v;
                    }
                    ah[rg][round * 4 + ks2] = h;
                }
            }
            asm volatile("s_waitcnt lgkmcnt(0)" ::: "memory");  // reads done before reuse
            __builtin_amdgcn_sched_barrier(0);
        }
    }
    #pragma unroll
    for (int rg = 0; rg < 2; ++rg) {
        zsq[rg] += __shfl_xor(zsq[rg], 16, 64);
        zsq[rg] += __shfl_xor(zsq[rg], 32, 64);
        if (l < 16) zsqL[w * 32 + rg * 16 + l] = zsq[rg];
    }

    float v1[8], v2[8];
    int   i1[8];
    #pragma unroll
    for (int s8 = 0; s8 < 8; ++s8) { v1[s8] = 3.4e38f; v2[s8] = 3.4e38f; i1[s8] = 0; }

    // all waves done using ring as z-scratch; drain ds ops, then begin e-staging
    asm volatile("s_waitcnt vmcnt(0) lgkmcnt(0)" ::: "memory");
    __syncthreads();
    stage_half4(ehc, lds,         0, w, l);
    stage_half4(ehc, lds + 16384, 1, w, l);
    stage_half4(ehc, lds + 32768, 2, w, l);

    // Phase h reads buf[h&3]; stage(h+3) (issued after the phase-h barrier) writes
    // buf[(h-1)&3], whose reads finished at that barrier. At the wait, stages h+1
    // and h+2 are outstanding (4 loads each) -> vmcnt(8) guarantees stage h landed.
    for (int h = 0; h < 30; ++h) {
        asm volatile("s_waitcnt vmcnt(8)" ::: "memory");
        __builtin_amdgcn_sched_barrier(0);
        __builtin_amdgcn_s_barrier();
        if (h < 29) stage_half4(ehc, lds + ((h + 3) & 3) * 16384, h + 3, w, l);
        compute_phase32(lds + (h & 3) * 16384, h, ah, reL, v1, v2, i1, lane15, lk);
    }
    asm volatile("s_waitcnt vmcnt(4)" ::: "memory");
    __builtin_amdgcn_sched_barrier(0);
    __builtin_amdgcn_s_barrier();
    compute_phase32(lds + (30 & 3) * 16384, 30, ah, reL, v1, v2, i1, lane15, lk);
    asm volatile("s_waitcnt vmcnt(0)" ::: "memory");
    __builtin_amdgcn_sched_barrier(0);
    __builtin_amdgcn_s_barrier();
    compute_phase32(lds + (31 & 3) * 16384, 31, ah, reL, v1, v2, i1, lane15, lk);

    // reduce across the 16 lanes holding different codes (same rows)
    #pragma unroll
    for (int off = 1; off < 16; off <<= 1) {
        #pragma unroll
        for (int s8 = 0; s8 < 8; ++s8) {
            float ov1 = __shfl_xor(v1[s8], off, 64);
            int   oi1 = __shfl_xor(i1[s8], off, 64);
            float ov2 = __shfl_xor(v2[s8], off, 64);
            float nv2 = fminf(fmaxf(v1[s8], ov1), fminf(v2[s8], ov2));
            if (ov1 < v1[s8] || (ov1 == v1[s8] && oi1 < i1[s8])) { v1[s8] = ov1; i1[s8] = oi1; }
            v2[s8] = nv2;
        }
    }
    if (lane15 == 0) {
        #pragma unroll
        for (int s8 = 0; s8 < 8; ++s8) {
            const int rg = s8 >> 2, rr = s8 & 3;
            const int row = w * 32 + rg * 16 + lk * 4 + rr;   // local row 0..127
            idsL[row] = i1[s8];
            const bool fl = (v2[s8] - v1[s8] < TAU);
            lossL[row] = fl ? zsqL[row] : (zsqL[row] + v1[s8]);
            if (fl) {
                int p = atomicAdd(cnt, 1);
                if (p < FLAGCAP) flags[p] = (r0 + row) | (i1[s8] << 16);
            }
        }
    }
    __syncthreads();

    // idx store (coalesced) + block loss partial (zsqL reused as 2-slot scratch)
    if (tid < 128) {
        idx[r0 + tid] = idsL[tid];
        float lv = lossL[tid];
        #pragma unroll
        for (int off = 32; off; off >>= 1) lv += __shfl_down(lv, off, 64);
        if (l == 0) zsqL[tid >> 6] = lv;
    }
    __syncthreads();
    if (tid == 0) lossP[blockIdx.x] = zsqL[0] + zsqL[1];

    // out-write: wave w covers c in [64w, 64w+64), all 128 rows
    {
        const int c0 = w * 64;
        float* ob = out + (size_t)b * ZD * TT + t0;
        #pragma unroll
        for (int half = 0; half < 2; ++half) {
            const int tt = half * 64 + l;
            const int ii = idsL[tt];
            const float4* er4 = (const float4*)(emb + (size_t)ii * ZD + c0);
            #pragma unroll
            for (int c4 = 0; c4 < 16; ++c4) {
                float4 ev = er4[c4];
                float* o0 = ob + (size_t)(c0 + c4 * 4) * TT + tt;
                o0[0]      = ev.x;
                o0[TT]     = ev.y;
                o0[2 * TT] = ev.z;
                o0[3 * TT] = ev.w;
            }
        }
    }
}

// ------- fixup (blocks 0..127) + sparsity (blocks 128..255); partials only -------
__global__ __launch_bounds__(256)
void vq_fixup_spar(const float* __restrict__ z, const float* __restrict__ emb,
                   const float* __restrict__ re, const int* __restrict__ cnt,
                   const int* __restrict__ flags, float* __restrict__ out,
                   int* __restrict__ idx, float* __restrict__ spar,
                   float* __restrict__ addP) {
    const int tid = threadIdx.x;
    const int w   = tid >> 6;
    const int lane = tid & 63;

    if (blockIdx.x >= 128) {
        // ---- sparsity: 8 rows/block, partial to spar[bid2] ----
        __shared__ __align__(16) float er[8][260];
        __shared__ float wmaxS[8][4];
        __shared__ float wsumS[8][4];
        __shared__ float shD[8];
        const int bid2 = blockIdx.x - 128;      // 0..127
        const int r0   = bid2 * 8;

        for (int i = tid; i < 8 * 256; i += 256) er[i >> 8][i & 255] = emb[(size_t)r0 * ZD + i];
        __syncthreads();

        float dots[4][8];
        #pragma unroll
        for (int cc = 0; cc < 4; ++cc) {
            const int c = cc * 256 + tid;
            const float4* ec = (const float4*)(emb + (size_t)c * ZD);
            float a[8] = {0.f,0.f,0.f,0.f,0.f,0.f,0.f,0.f};
            for (int k4 = 0; k4 < ZD / 4; ++k4) {
                float4 e4 = ec[k4];
                #pragma unroll
                for (int r = 0; r < 8; ++r) {
                    const float* a4 = &er[r][k4 * 4];
                    a[r] = fmaf(e4.x, a4[0], fmaf(e4.y, a4[1],
                           fmaf(e4.z, a4[2], fmaf(e4.w, a4[3], a[r]))));
                }
            }
            #pragma unroll
            for (int r = 0; r < 8; ++r) dots[cc][r] = a[r];
            const int gr = c - r0;
            if (gr >= 0 && gr < 8) shD[gr] = a[gr];
        }
        #pragma unroll
        for (int r = 0; r < 8; ++r) {
            float m = fmaxf(fmaxf(dots[0][r], dots[1][r]), fmaxf(dots[2][r], dots[3][r]));
            #pragma unroll
            for (int off = 32; off; off >>= 1) m = fmaxf(m, __shfl_xor(m, off, 64));
            if (lane == 0) wmaxS[r][w] = m;
        }
        __syncthreads();
        #pragma unroll
        for (int r = 0; r < 8; ++r) {
            const float M = fmaxf(fmaxf(wmaxS[r][0], wmaxS[r][1]),
                                  fmaxf(wmaxS[r][2], wmaxS[r][3]));
            float se = expf(dots[0][r] - M) + expf(dots[1][r] - M)
                     + expf(dots[2][r] - M) + expf(dots[3][r] - M);
            #pragma unroll
            for (int off = 32; off; off >>= 1) se += __shfl_xor(se, off, 64);
            if (lane == 0) wsumS[r][w] = se;
        }
        __syncthreads();
        if (tid == 0) {
            float acc = 0.f;
            #pragma unroll
            for (int r = 0; r < 8; ++r) {
                const float M = fmaxf(fmaxf(wmaxS[r][0], wmaxS[r][1]),
                                      fmaxf(wmaxS[r][2], wmaxS[r][3]));
                const float S = wsumS[r][0] + wsumS[r][1] + wsumS[r][2] + wsumS[r][3];
                acc += M + logf(S) - shD[r];
            }
            spar[bid2] = acc;
        }
        return;
    }

    // ---- fixup: exact fp32 rescore, 8 flagged rows per pass, 128 blocks ----
    __shared__ __align__(16) float zs[8][ZD];
    __shared__ u64 sb[4][8];
    __shared__ int nwS[8];
    __shared__ float addS;
    int n = cnt[0];
    if (n > FLAGCAP) n = FLAGCAP;
    float blkLoss = 0.f;    // meaningful at tid==0 only

    for (int base = blockIdx.x * 8; base < n; base += 128 * 8) {
        const int nr = (n - base < 8) ? (n - base) : 8;
        __syncthreads();
        for (int i = tid; i < nr * 256; i += 256) {
            const int r = i >> 8, k = i & 255;
            const int rowg = flags[base + r] & 0xFFFF;
            zs[r][k] = z[(size_t)(rowg >> 12) * ZD * TT + (size_t)k * TT + (rowg & 4095)];
        }
        __syncthreads();

        u64 best[8];
        #pragma unroll
        for (int r = 0; r < 8; ++r) best[r] = 0xFFFFFFFFFFFFFFFFull;

        for (int cc = 0; cc < 4; ++cc) {
            const int c = cc * 256 + tid;
            const float4* ec = (const float4*)(emb + (size_t)c * ZD);
            float a[8] = {0.f,0.f,0.f,0.f,0.f,0.f,0.f,0.f};
            for (int k4 = 0; k4 < ZD / 4; ++k4) {
                float4 e4 = ec[k4];
                #pragma unroll
                for (int r = 0; r < 8; ++r) {
                    const float* a4 = &zs[r][k4 * 4];
                    a[r] = fmaf(e4.x, a4[0], fmaf(e4.y, a4[1],
                           fmaf(e4.z, a4[2], fmaf(e4.w, a4[3], a[r]))));
                }
            }
            const float rc = re[c];
            #pragma unroll
            for (int r = 0; r < 8; ++r) {
                if (r < nr) {
                    float s = fmaf(-2.f, a[r], rc);
                    u64 pk = ((u64)flip32(s) << 32) | (u32)c;
                    if (pk < best[r]) best[r] = pk;
                }
            }
        }
        #pragma unroll
        for (int r = 0; r < 8; ++r) {
            if (r < nr) {
                u64 bv = best[r];
                #pragma unroll
                for (int off = 32; off; off >>= 1) {
                    u64 o = (u64)__shfl_xor((long long)bv, off, 64);
                    if (o < bv) bv = o;
                }
                if (lane == 0) sb[w][r] = bv;
            }
        }
        __syncthreads();
        if (tid == 0) addS = 0.f;
        __syncthreads();
        if (tid < nr) {
            u64 m = sb[0][tid];
            if (sb[1][tid] < m) m = sb[1][tid];
            if (sb[2][tid] < m) m = sb[2][tid];
            if (sb[3][tid] < m) m = sb[3][tid];
            const int nc  = (int)(u32)(m & 0xFFFFFFFFull);
            const float s = unflip32((u32)(m >> 32));
            const int rowg = flags[base + tid] & 0xFFFF;
            const int old  = (flags[base + tid] >> 16) & 1023;
            atomicAdd(&addS, s);
            if (nc != old) { idx[rowg] = nc; nwS[tid] = nc; }
            else nwS[tid] = -1;
        }
        __syncthreads();
        if (tid == 0) blkLoss += addS;
        for (int r = 0; r < nr; ++r) {
            const int nw = nwS[r];
            if (nw >= 0) {
                const int rowg = flags[base + r] & 0xFFFF;
                out[(size_t)(rowg >> 12) * ZD * TT + (size_t)tid * TT + (rowg & 4095)]
                    = emb[(size_t)nw * ZD + tid];
            }
        }
    }
    if (tid == 0) addP[blockIdx.x] = blkLoss;
}

// ---------------- final: loss sums + histogram->perplexity + sparsity sum ----------------
__global__ __launch_bounds__(256)
void vq_final_kernel(const int* __restrict__ idx, const float* __restrict__ spar,
                     const float* __restrict__ lossP, const float* __restrict__ addP,
                     float* __restrict__ scal) {
    __shared__ int   histL[1024];
    __shared__ float red[256];
    const int tid = threadIdx.x;

    // histogram from corrected idx (coalesced reads, LDS atomics)
    #pragma unroll
    for (int j = 0; j < 4; ++j) histL[j * 256 + tid] = 0;
    __syncthreads();
    #pragma unroll 8
    for (int i = 0; i < 256; ++i)
        atomicAdd(&histL[idx[i * 256 + tid]], 1);
    __syncthreads();
    float s = 0.f;
    #pragma unroll
    for (int j = 0; j < 4; ++j) {
        float p = (float)histL[j * 256 + tid] * (1.0f / (float)NROWS);
        s -= p * logf(p + 1e-10f);
    }
    red[tid] = s;
    __syncthreads();
    for (int st = 128; st; st >>= 1) {
        if (tid < st) red[tid] += red[tid + st];
        __syncthreads();
    }
    if (tid == 0) scal[2] = expf(red[0]);
    __syncthreads();

    // loss: 512 argmin partials + 128 fixup partials
    red[tid] = lossP[tid] + lossP[256 + tid] + ((tid < 128) ? addP[tid] : 0.f);
    __syncthreads();
    for (int st = 128; st; st >>= 1) {
        if (tid < st) red[tid] += red[tid + st];
        __syncthreads();
    }
    if (tid == 0) { scal[0] = red[0]; scal[1] = red[0]; }
    __syncthreads();

    // sparsity: 128 partials
    red[tid] = (tid < 128) ? spar[tid] : 0.f;
    __syncthreads();
    for (int st = 128; st; st >>= 1) {
        if (tid < st) red[tid] += red[tid + st];
        __syncthreads();
    }
    if (tid == 0) scal[3] = red[0] * (1.0f / (float)KC);
}

extern "C" void kernel_launch(void* const* d_in, const int* in_sizes, int n_in,
                              void* d_out, int out_size, void* d_ws, size_t ws_size,
                              hipStream_t stream) {
    const float* z   = (const float*)d_in[0];
    const float* emb = (const float*)d_in[1];
    float* out = (float*)d_out;
    const size_t NOUT = (size_t)BB * ZD * TT;    // 16777216
    float* scal = out + NOUT;                    // [qut, enc, perp, sparsity]

    float* re    = (float*)d_ws;                 // 1024 f32
    int*   cnt   = (int*)(re + KC);              // 4 i32
    int*   flags = cnt + 4;                      // FLAGCAP i32
    float* spar  = (float*)(flags + FLAGCAP);    // 128 f32
    float* lossP = spar + 128;                   // 512 f32
    float* addP  = lossP + 512;                  // 128 f32
    int*   idx   = (int*)(addP + 128);           // 65536 i32
    _Float16* eh = (_Float16*)(idx + NROWS);     // 1024*256 f16

    vq_prep_kernel<<<256, 256, 0, stream>>>(emb, eh, re, cnt);
    vq_argmin_mfma<<<NROWS / 128, 256, 0, stream>>>(z, eh, emb, re, out, lossP, idx,
                                                    cnt, flags);
    vq_fixup_spar<<<256, 256, 0, stream>>>(z, emb, re, cnt, flags, out, idx, spar, addP);
    vq_final_kernel<<<1, 256, 0, stream>>>(idx, spar, lossP, addP, scal);
}

// Round 19
// 169.930 us; speedup vs baseline: 1.7272x; 1.2533x over previous
//
#include <hip/hip_runtime.h>
#include <math.h>

typedef unsigned int u32;
typedef unsigned long long u64;
typedef _Float16 f16x8 __attribute__((ext_vector_type(8)));
typedef _Float16 f16x4 __attribute__((ext_vector_type(4)));
typedef float f32x4 __attribute__((ext_vector_type(4)));
typedef __attribute__((address_space(1))) const char gch;
typedef __attribute__((address_space(3))) char lch;

#define ZD 256      // z_dim (C)
#define KC 1024     // number of codes
#define TT 4096     // T
#define BB 16       // B
#define NROWS (BB*TT)     // 65536
#define TAU 0.12f         // margin threshold (~6 sigma of fp16 pairwise err)
#define FLAGCAP 32768

__device__ __forceinline__ u32 flip32(float s) {
    int i = __float_as_int(s);
    return (u32)(i ^ ((i >> 31) | 0x80000000));
}
__device__ __forceinline__ float unflip32(u32 u) {
    int m = (~(((int)u) >> 31)) | 0x80000000;
    return __int_as_float((int)(u ^ (u32)m));
}

// ---------------- prep: zero cnt, re=||e||^2, emb->fp16 ----------------
__global__ __launch_bounds__(256)
void vq_prep_kernel(const float* __restrict__ emb, _Float16* __restrict__ eh,
                    float* __restrict__ re, int* __restrict__ cnt) {
    int gid = blockIdx.x * 256 + threadIdx.x;
    if (gid < 2) cnt[gid] = 0;      // cnt[0]=flag count

    int code = gid >> 6;   // one wave per code
    int lane = threadIdx.x & 63;
    float4 v = *(const float4*)(emb + (size_t)code * ZD + lane * 4);
    float s = v.x*v.x + v.y*v.y + v.z*v.z + v.w*v.w;
    #pragma unroll
    for (int off = 32; off; off >>= 1) s += __shfl_down(s, off, 64);
    if (lane == 0) re[code] = s;

    f16x4 hv;
    hv[0] = (_Float16)v.x; hv[1] = (_Float16)v.y;
    hv[2] = (_Float16)v.z; hv[3] = (_Float16)v.w;
    *(f16x4*)(eh + (size_t)code * ZD + lane * 4) = hv;
}

// ---- stage one 32-code half-tile (16KB) via global_load_lds; 4 waves x 4 loads ----
__device__ __forceinline__ void stage_half4(const char* ehc, char* dstbase,
                                            int h, int w, int l) {
    const int srow = h * 16384;             // 32 codes * 512B
    #pragma unroll
    for (int j = 0; j < 4; ++j) {
        const int gi  = w * 4 + j;          // 0..15
        const int c   = 2 * gi + (l >> 5);  // local code this lane's 16B lands in
        const int kbs = (l & 31) * 16;
        const int off = srow + c * 512 + (kbs ^ ((c & 7) << 4));
        __builtin_amdgcn_global_load_lds((gch*)(ehc + off),
                                         (lch*)(dstbase + gi * 1024), 16, 0, 0);
    }
}

// ---- one 32-code compute phase: 16 ds_read_b128 + 32 MFMA (2 rowgroups) ----
__device__ __forceinline__ void compute_phase32(const char* hb, int h,
                                                const f16x8 (&ah)[2][8], const float* reL,
                                                float (&v1)[8], float (&v2)[8], int (&i1)[8],
                                                int lane15, int lk) {
    #pragma unroll
    for (int cg = 0; cg < 2; ++cg) {
        const int c  = cg * 16 + lane15;        // local code 0..31
        const int sw = (lane15 & 7) << 4;       // c&7 == lane15&7
        f16x8 bh[8];
        #pragma unroll
        for (int ks = 0; ks < 8; ++ks)
            bh[ks] = *(const f16x8*)(hb + c * 512 + ((lk * 16 + ks * 64) ^ sw));

        f32x4 a0 = {0.f, 0.f, 0.f, 0.f};
        f32x4 a1 = {0.f, 0.f, 0.f, 0.f};
        __builtin_amdgcn_s_setprio(1);
        #pragma unroll
        for (int ks = 0; ks < 8; ++ks) {
            a0 = __builtin_amdgcn_mfma_f32_16x16x32_f16(ah[0][ks], bh[ks], a0, 0, 0, 0);
            a1 = __builtin_amdgcn_mfma_f32_16x16x32_f16(ah[1][ks], bh[ks], a1, 0, 0, 0);
        }
        __builtin_amdgcn_s_setprio(0);

        const int codeg = h * 32 + c;
        const float rc = reL[codeg];
        #pragma unroll
        for (int r = 0; r < 4; ++r) {
            float s0 = fmaf(-2.f, a0[r], rc);
            float n2a = fminf(fmaxf(v1[r], s0), v2[r]);          // med3(v1,v2,s0)
            i1[r] = (s0 < v1[r]) ? codeg : i1[r];
            v1[r] = fminf(v1[r], s0);
            v2[r] = n2a;
            float s1 = fmaf(-2.f, a1[r], rc);
            float n2b = fminf(fmaxf(v1[4 + r], s1), v2[4 + r]);
            i1[4 + r] = (s1 < v1[4 + r]) ? codeg : i1[4 + r];
            v1[4 + r] = fminf(v1[4 + r], s1);
            v2[4 + r] = n2b;
        }
    }
}

// ---------------- fused argmin + out-write + loss partial + idx ----------------
// 512 blocks x 256 threads (4 waves). Block: 128 rows; wave w: rows [32w,32w+32).
// z staged coalesced via global_load_lds; 32 phases, ring-4 LDS, counted vmcnt(8).
// Loss emitted as per-block partial lossP[bid] (no same-address atomics).
__global__ __launch_bounds__(256, 2)
void vq_argmin_mfma(const float* __restrict__ z, const _Float16* __restrict__ eh,
                    const float* __restrict__ emb, const float* __restrict__ re,
                    float* __restrict__ out, float* __restrict__ lossP,
                    int* __restrict__ idx, int* __restrict__ cnt,
                    int* __restrict__ flags) {
    __shared__ __align__(16) char lds[71168];   // ring 4x16KB | reL 4KB | tails
    float* reL   = (float*)(lds + 65536);   // 1024 f32
    float* zsqL  = (float*)(lds + 69632);   // 128 f32 (reused as wave-loss scratch)
    int*   idsL  = (int*)  (lds + 70144);   // 128 i32
    float* lossL = (float*)(lds + 70656);   // 128 f32

    const int tid = threadIdx.x;
    const int w   = tid >> 6;       // 0..3
    const int l   = tid & 63;
    const int lane15 = l & 15;
    const int lk     = l >> 4;
    const int r0  = blockIdx.x * 128;
    const int b   = r0 >> 12;
    const int t0  = r0 & 4095;
    const char* ehc = (const char*)eh;

    *(float4*)(reL + tid * 4) = *(const float4*)(re + tid * 4);

    // ---- z prologue: coalesced glds staging into ring[w] (16KB), 2 rounds of 128 c ----
    f16x8 ah[2][8];
    float zsq[2] = {0.f, 0.f};
    {
        const char* zb = (const char*)(z + (size_t)b * ZD * TT + t0 + w * 32);
        char* zdst = lds + w * 16384;
        #pragma unroll
        for (int round = 0; round < 2; ++round) {
            #pragma unroll
            for (int j = 0; j < 16; ++j) {
                const int c  = round * 128 + j * 8 + (l >> 3);
                const int tb = (l & 7) * 16;
                const char* src = zb + (size_t)c * TT * 4 + tb;
                __builtin_amdgcn_global_load_lds((gch*)src, (lch*)(zdst + j * 1024),
                                                 16, 0, 0);
            }
            asm volatile("s_waitcnt vmcnt(0)" ::: "memory");
            __builtin_amdgcn_sched_barrier(0);
            #pragma unroll
            for (int rg = 0; rg < 2; ++rg) {
                const int tw = rg * 16 + lane15;
                #pragma unroll
                for (int ks2 = 0; ks2 < 4; ++ks2) {
                    const int cl = ks2 * 32 + lk * 8;   // local c within round
                    f16x8 h;
                    #pragma unroll
                    for (int j = 0; j < 8; ++j) {
                        float v = *(const float*)(zdst + (cl + j) * 128 + tw * 4);
                        zsq[rg] = fmaf(v, v, zsq[rg]);
                        h[j] = (_Float16)v;
                    }
                    ah[rg][round * 4 + ks2] = h;
                }
            }
            asm volatile("s_waitcnt lgkmcnt(0)" ::: "memory");  // reads done before reuse
            __builtin_amdgcn_sched_barrier(0);
        }
    }
    #pragma unroll
    for (int rg = 0; rg < 2; ++rg) {
        zsq[rg] += __shfl_xor(zsq[rg], 16, 64);
        zsq[rg] += __shfl_xor(zsq[rg], 32, 64);
        if (l < 16) zsqL[w * 32 + rg * 16 + l] = zsq[rg];
    }

    float v1[8], v2[8];
    int   i1[8];
    #pragma unroll
    for (int s8 = 0; s8 < 8; ++s8) { v1[s8] = 3.4e38f; v2[s8] = 3.4e38f; i1[s8] = 0; }

    // all waves done using ring as z-scratch; drain ds ops, then begin e-staging
    asm volatile("s_waitcnt vmcnt(0) lgkmcnt(0)" ::: "memory");
    __syncthreads();
    stage_half4(ehc, lds,         0, w, l);
    stage_half4(ehc, lds + 16384, 1, w, l);
    stage_half4(ehc, lds + 32768, 2, w, l);

    // Phase h reads buf[h&3]; stage(h+3) (issued after the phase-h barrier) writes
    // buf[(h-1)&3], whose reads finished at that barrier. At the wait, stages h+1
    // and h+2 are outstanding (4 loads each) -> vmcnt(8) guarantees stage h landed.
    for (int h = 0; h < 30; ++h) {
        asm volatile("s_waitcnt vmcnt(8)" ::: "memory");
        __builtin_amdgcn_sched_barrier(0);
        __builtin_amdgcn_s_barrier();
        if (h < 29) stage_half4(ehc, lds + ((h + 3) & 3) * 16384, h + 3, w, l);
        compute_phase32(lds + (h & 3) * 16384, h, ah, reL, v1, v2, i1, lane15, lk);
    }
    asm volatile("s_waitcnt vmcnt(4)" ::: "memory");
    __builtin_amdgcn_sched_barrier(0);
    __builtin_amdgcn_s_barrier();
    compute_phase32(lds + (30 & 3) * 16384, 30, ah, reL, v1, v2, i1, lane15, lk);
    asm volatile("s_waitcnt vmcnt(0)" ::: "memory");
    __builtin_amdgcn_sched_barrier(0);
    __builtin_amdgcn_s_barrier();
    compute_phase32(lds + (31 & 3) * 16384, 31, ah, reL, v1, v2, i1, lane15, lk);

    // reduce across the 16 lanes holding different codes (same rows)
    #pragma unroll
    for (int off = 1; off < 16; off <<= 1) {
        #pragma unroll
        for (int s8 = 0; s8 < 8; ++s8) {
            float ov1 = __shfl_xor(v1[s8], off, 64);
            int   oi1 = __shfl_xor(i1[s8], off, 64);
            float ov2 = __shfl_xor(v2[s8], off, 64);
            float nv2 = fminf(fmaxf(v1[s8], ov1), fminf(v2[s8], ov2));
            if (ov1 < v1[s8] || (ov1 == v1[s8] && oi1 < i1[s8])) { v1[s8] = ov1; i1[s8] = oi1; }
            v2[s8] = nv2;
        }
    }
    if (lane15 == 0) {
        #pragma unroll
        for (int s8 = 0; s8 < 8; ++s8) {
            const int rg = s8 >> 2, rr = s8 & 3;
            const int row = w * 32 + rg * 16 + lk * 4 + rr;   // local row 0..127
            idsL[row] = i1[s8];
            const bool fl = (v2[s8] - v1[s8] < TAU);
            lossL[row] = fl ? zsqL[row] : (zsqL[row] + v1[s8]);
            if (fl) {
                int p = atomicAdd(cnt, 1);
                if (p < FLAGCAP) flags[p] = (r0 + row) | (i1[s8] << 16);
            }
        }
    }
    __syncthreads();

    // idx store (coalesced) + block loss partial (zsqL reused as 2-slot scratch)
    if (tid < 128) {
        idx[r0 + tid] = idsL[tid];
        float lv = lossL[tid];
        #pragma unroll
        for (int off = 32; off; off >>= 1) lv += __shfl_down(lv, off, 64);
        if (l == 0) zsqL[tid >> 6] = lv;
    }
    __syncthreads();
    if (tid == 0) lossP[blockIdx.x] = zsqL[0] + zsqL[1];

    // out-write: wave w covers c in [64w, 64w+64), all 128 rows
    {
        const int c0 = w * 64;
        float* ob = out + (size_t)b * ZD * TT + t0;
        #pragma unroll
        for (int half = 0; half < 2; ++half) {
            const int tt = half * 64 + l;
            const int ii = idsL[tt];
            const float4* er4 = (const float4*)(emb + (size_t)ii * ZD + c0);
            #pragma unroll
            for (int c4 = 0; c4 < 16; ++c4) {
                float4 ev = er4[c4];
                float* o0 = ob + (size_t)(c0 + c4 * 4) * TT + tt;
                o0[0]      = ev.x;
                o0[TT]     = ev.y;
                o0[2 * TT] = ev.z;
                o0[3 * TT] = ev.w;
            }
        }
    }
}

// ------- fixup (blocks 0..127) + sparsity (blocks 128..255); partials only -------
__global__ __launch_bounds__(256)
void vq_fixup_spar(const float* __restrict__ z, const float* __restrict__ emb,
                   const float* __restrict__ re, const int* __restrict__ cnt,
                   const int* __restrict__ flags, float* __restrict__ out,
                   int* __restrict__ idx, float* __restrict__ spar,
                   float* __restrict__ addP) {
    const int tid = threadIdx.x;
    const int w   = tid >> 6;
    const int lane = tid & 63;

    if (blockIdx.x >= 128) {
        // ---- sparsity: 8 rows/block, partial to spar[bid2] ----
        __shared__ __align__(16) float er[8][260];
        __shared__ float wmaxS[8][4];
        __shared__ float wsumS[8][4];
        __shared__ float shD[8];
        const int bid2 = blockIdx.x - 128;      // 0..127
        const int r0   = bid2 * 8;

        for (int i = tid; i < 8 * 256; i += 256) er[i >> 8][i & 255] = emb[(size_t)r0 * ZD + i];
        __syncthreads();

        float dots[4][8];
        #pragma unroll
        for (int cc = 0; cc < 4; ++cc) {
            const int c = cc * 256 + tid;
            const float4* ec = (const float4*)(emb + (size_t)c * ZD);
            float a[8] = {0.f,0.f,0.f,0.f,0.f,0.f,0.f,0.f};
            for (int k4 = 0; k4 < ZD / 4; ++k4) {
                float4 e4 = ec[k4];
                #pragma unroll
                for (int r = 0; r < 8; ++r) {
                    const float* a4 = &er[r][k4 * 4];
                    a[r] = fmaf(e4.x, a4[0], fmaf(e4.y, a4[1],
                           fmaf(e4.z, a4[2], fmaf(e4.w, a4[3], a[r]))));
                }
            }
            #pragma unroll
            for (int r = 0; r < 8; ++r) dots[cc][r] = a[r];
            const int gr = c - r0;
            if (gr >= 0 && gr < 8) shD[gr] = a[gr];
        }
        #pragma unroll
        for (int r = 0; r < 8; ++r) {
            float m = fmaxf(fmaxf(dots[0][r], dots[1][r]), fmaxf(dots[2][r], dots[3][r]));
            #pragma unroll
            for (int off = 32; off; off >>= 1) m = fmaxf(m, __shfl_xor(m, off, 64));
            if (lane == 0) wmaxS[r][w] = m;
        }
        __syncthreads();
        #pragma unroll
        for (int r = 0; r < 8; ++r) {
            const float M = fmaxf(fmaxf(wmaxS[r][0], wmaxS[r][1]),
                                  fmaxf(wmaxS[r][2], wmaxS[r][3]));
            float se = expf(dots[0][r] - M) + expf(dots[1][r] - M)
                     + expf(dots[2][r] - M) + expf(dots[3][r] - M);
            #pragma unroll
            for (int off = 32; off; off >>= 1) se += __shfl_xor(se, off, 64);
            if (lane == 0) wsumS[r][w] = se;
        }
        __syncthreads();
        if (tid == 0) {
            float acc = 0.f;
            #pragma unroll
            for (int r = 0; r < 8; ++r) {
                const float M = fmaxf(fmaxf(wmaxS[r][0], wmaxS[r][1]),
                                      fmaxf(wmaxS[r][2], wmaxS[r][3]));
                const float S = wsumS[r][0] + wsumS[r][1] + wsumS[r][2] + wsumS[r][3];
                acc += M + logf(S) - shD[r];
            }
            spar[bid2] = acc;
        }
        return;
    }

    // ---- fixup: exact fp32 rescore, 8 flagged rows per pass, 128 blocks ----
    __shared__ __align__(16) float zs[8][ZD];
    __shared__ u64 sb[4][8];
    __shared__ int nwS[8];
    __shared__ float addS;
    int n = cnt[0];
    if (n > FLAGCAP) n = FLAGCAP;
    float blkLoss = 0.f;    // meaningful at tid==0 only

    for (int base = blockIdx.x * 8; base < n; base += 128 * 8) {
        const int nr = (n - base < 8) ? (n - base) : 8;
        __syncthreads();
        for (int i = tid; i < nr * 256; i += 256) {
            const int r = i >> 8, k = i & 255;
            const int rowg = flags[base + r] & 0xFFFF;
            zs[r][k] = z[(size_t)(rowg >> 12) * ZD * TT + (size_t)k * TT + (rowg & 4095)];
        }
        __syncthreads();

        u64 best[8];
        #pragma unroll
        for (int r = 0; r < 8; ++r) best[r] = 0xFFFFFFFFFFFFFFFFull;

        for (int cc = 0; cc < 4; ++cc) {
            const int c = cc * 256 + tid;
            const float4* ec = (const float4*)(emb + (size_t)c * ZD);
            float a[8] = {0.f,0.f,0.f,0.f,0.f,0.f,0.f,0.f};
            for (int k4 = 0; k4 < ZD / 4; ++k4) {
                float4 e4 = ec[k4];
                #pragma unroll
                for (int r = 0; r < 8; ++r) {
                    const float* a4 = &zs[r][k4 * 4];
                    a[r] = fmaf(e4.x, a4[0], fmaf(e4.y, a4[1],
                           fmaf(e4.z, a4[2], fmaf(e4.w, a4[3], a[r]))));
                }
            }
            const float rc = re[c];
            #pragma unroll
            for (int r = 0; r < 8; ++r) {
                if (r < nr) {
                    float s = fmaf(-2.f, a[r], rc);
                    u64 pk = ((u64)flip32(s) << 32) | (u32)c;
                    if (pk < best[r]) best[r] = pk;
                }
            }
        }
        #pragma unroll
        for (int r = 0; r < 8; ++r) {
            if (r < nr) {
                u64 bv = best[r];
                #pragma unroll
                for (int off = 32; off; off >>= 1) {
                    u64 o = (u64)__shfl_xor((long long)bv, off, 64);
                    if (o < bv) bv = o;
                }
                if (lane == 0) sb[w][r] = bv;
            }
        }
        __syncthreads();
        if (tid == 0) addS = 0.f;
        __syncthreads();
        if (tid < nr) {
            u64 m = sb[0][tid];
            if (sb[1][tid] < m) m = sb[1][tid];
            if (sb[2][tid] < m) m = sb[2][tid];
            if (sb[3][tid] < m) m = sb[3][tid];
            const int nc  = (int)(u32)(m & 0xFFFFFFFFull);
            const float s = unflip32((u32)(m >> 32));
            const int rowg = flags[base + tid] & 0xFFFF;
            const int old  = (flags[base + tid] >> 16) & 1023;
            atomicAdd(&addS, s);
            if (nc != old) { idx[rowg] = nc; nwS[tid] = nc; }
            else nwS[tid] = -1;
        }
        __syncthreads();
        if (tid == 0) blkLoss += addS;
        for (int r = 0; r < nr; ++r) {
            const int nw = nwS[r];
            if (nw >= 0) {
                const int rowg = flags[base + r] & 0xFFFF;
                out[(size_t)(rowg >> 12) * ZD * TT + (size_t)tid * TT + (rowg & 4095)]
                    = emb[(size_t)nw * ZD + tid];
            }
        }
    }
    if (tid == 0) addP[blockIdx.x] = blkLoss;
}

// ---------------- final: 1024 thr, 4 LDS sub-histograms -> perplexity; sums ----------------
__global__ __launch_bounds__(1024)
void vq_final_kernel(const int* __restrict__ idx, const float* __restrict__ spar,
                     const float* __restrict__ lossP, const float* __restrict__ addP,
                     float* __restrict__ scal) {
    __shared__ int   histL[4][1024];
    __shared__ float red[1024];
    const int tid = threadIdx.x;
    const int g   = tid >> 8;       // 4 sub-histograms (4 waves each)

    #pragma unroll
    for (int j = 0; j < 4; ++j) histL[j][tid & 255 | ((tid >> 8) << 8)] = 0;  // all 4096 ints
    // simpler full clear:
    histL[0][tid] = 0; histL[1][tid] = 0; histL[2][tid] = 0; histL[3][tid] = 0;
    __syncthreads();
    #pragma unroll 4
    for (int i = 0; i < 64; ++i)
        atomicAdd(&histL[g][idx[i * 1024 + tid]], 1);
    __syncthreads();
    const int hc = histL[0][tid] + histL[1][tid] + histL[2][tid] + histL[3][tid];
    float p = (float)hc * (1.0f / (float)NROWS);
    red[tid] = -p * logf(p + 1e-10f);
    __syncthreads();
    for (int st = 512; st; st >>= 1) {
        if (tid < st) red[tid] += red[tid + st];
        __syncthreads();
    }
    if (tid == 0) scal[2] = expf(red[0]);
    __syncthreads();

    // loss: 512 argmin partials + 128 fixup partials
    red[tid] = (tid < 512 ? lossP[tid] : 0.f) + ((tid < 128) ? addP[tid] : 0.f);
    __syncthreads();
    for (int st = 512; st; st >>= 1) {
        if (tid < st) red[tid] += red[tid + st];
        __syncthreads();
    }
    if (tid == 0) { scal[0] = red[0]; scal[1] = red[0]; }
    __syncthreads();

    // sparsity: 128 partials
    red[tid] = (tid < 128) ? spar[tid] : 0.f;
    __syncthreads();
    for (int st = 512; st; st >>= 1) {
        if (tid < st) red[tid] += red[tid + st];
        __syncthreads();
    }
    if (tid == 0) scal[3] = red[0] * (1.0f / (float)KC);
}

extern "C" void kernel_launch(void* const* d_in, const int* in_sizes, int n_in,
                              void* d_out, int out_size, void* d_ws, size_t ws_size,
                              hipStream_t stream) {
    const float* z   = (const float*)d_in[0];
    const float* emb = (const float*)d_in[1];
    float* out = (float*)d_out;
    const size_t NOUT = (size_t)BB * ZD * TT;    // 16777216
    float* scal = out + NOUT;                    // [qut, enc, perp, sparsity]

    float* re    = (float*)d_ws;                 // 1024 f32
    int*   cnt   = (int*)(re + KC);              // 4 i32
    int*   flags = cnt + 4;                      // FLAGCAP i32
    float* spar  = (float*)(flags + FLAGCAP);    // 128 f32
    float* lossP = spar + 128;                   // 512 f32
    float* addP  = lossP + 512;                  // 128 f32
    int*   idx   = (int*)(addP + 128);           // 65536 i32
    _Float16* eh = (_Float16*)(idx + NROWS);     // 1024*256 f16

    vq_prep_kernel<<<256, 256, 0, stream>>>(emb, eh, re, cnt);
    vq_argmin_mfma<<<NROWS / 128, 256, 0, stream>>>(z, eh, emb, re, out, lossP, idx,
                                                    cnt, flags);
    vq_fixup_spar<<<256, 256, 0, stream>>>(z, emb, re, cnt, flags, out, idx, spar, addP);
    vq_final_kernel<<<1, 1024, 0, stream>>>(idx, spar, lossP, addP, scal);
}